// Round 1
// baseline (318.796 us; speedup 1.0000x reference)
//
#include <hip/hip_runtime.h>
#include <stdint.h>

#define NCOL 16
#define RGRID 2048
typedef float v4f __attribute__((ext_vector_type(4)));

// Pass 1: column-wise min/max over x[N,16] row-major, read as float4.
// Grid reduction is contention-free: each block stores its 32 partials into
// its own workspace slot (no init required -- every slot is written before the
// last-arriving block reads them), then the last block (threadfence+counter
// pattern) reduces all slots and writes the final scale/offset directly.
// This replaces 65,536 atomicMin RMWs onto two cache lines (suspected ~25+ us
// of serialization) with 2048 uncontended 128-B row writes.
__global__ void __launch_bounds__(256) colreduce(const v4f* __restrict__ x,
                                                 float* __restrict__ finals,   // [32]: scale[16], off[16]
                                                 float* __restrict__ slots,    // [RGRID][32]: min[16], max[16]
                                                 uint32_t* __restrict__ counter,
                                                 int n4) {
    int tid = blockIdx.x * blockDim.x + threadIdx.x;
    int stride = gridDim.x * blockDim.x;   // 256-thread blocks -> multiple of 4
    float mn0 = INFINITY, mn1 = INFINITY, mn2 = INFINITY, mn3 = INFINITY;
    float mx0 = -INFINITY, mx1 = -INFINITY, mx2 = -INFINITY, mx3 = -INFINITY;
    for (int i = tid; i < n4; i += stride) {
        v4f v = x[i];   // regular load: populates L2/L3 so pass 2 hits L3
        mn0 = fminf(mn0, v.x); mx0 = fmaxf(mx0, v.x);
        mn1 = fminf(mn1, v.y); mx1 = fmaxf(mx1, v.y);
        mn2 = fminf(mn2, v.z); mx2 = fmaxf(mx2, v.z);
        mn3 = fminf(mn3, v.w); mx3 = fmaxf(mx3, v.w);
    }
    // Butterfly across the 16 lanes sharing the same (lane&3) column group.
    #pragma unroll
    for (int off = 4; off < 64; off <<= 1) {
        mn0 = fminf(mn0, __shfl_xor(mn0, off)); mx0 = fmaxf(mx0, __shfl_xor(mx0, off));
        mn1 = fminf(mn1, __shfl_xor(mn1, off)); mx1 = fmaxf(mx1, __shfl_xor(mx1, off));
        mn2 = fminf(mn2, __shfl_xor(mn2, off)); mx2 = fmaxf(mx2, __shfl_xor(mx2, off));
        mn3 = fminf(mn3, __shfl_xor(mn3, off)); mx3 = fmaxf(mx3, __shfl_xor(mx3, off));
    }
    __shared__ float smn[4][NCOL], smx[4][NCOL];
    int wave = threadIdx.x >> 6;
    int lane = threadIdx.x & 63;
    if (lane < 4) {           // lane l holds the full wave reduction for group l
        int g = lane * 4;
        smn[wave][g + 0] = mn0; smx[wave][g + 0] = mx0;
        smn[wave][g + 1] = mn1; smx[wave][g + 1] = mx1;
        smn[wave][g + 2] = mn2; smx[wave][g + 2] = mx2;
        smn[wave][g + 3] = mn3; smx[wave][g + 3] = mx3;
    }
    __syncthreads();
    if (threadIdx.x < NCOL) {
        int c = threadIdx.x;
        float m = fminf(fminf(smn[0][c], smn[1][c]), fminf(smn[2][c], smn[3][c]));
        float M = fmaxf(fmaxf(smx[0][c], smx[1][c]), fmaxf(smx[2][c], smx[3][c]));
        size_t base = (size_t)blockIdx.x * 32;
        // agent-scope stores: bypass the (non-cross-coherent) per-XCD caches
        __hip_atomic_store(&slots[base + c],        m, __ATOMIC_RELAXED, __HIP_MEMORY_SCOPE_AGENT);
        __hip_atomic_store(&slots[base + NCOL + c], M, __ATOMIC_RELAXED, __HIP_MEMORY_SCOPE_AGENT);
    }
    // canonical last-block-done pattern: per-thread device fence BEFORE the
    // block barrier so every store is device-visible before the counter bump.
    __threadfence();
    __syncthreads();
    __shared__ bool s_last;
    if (threadIdx.x == 0)
        s_last = (atomicAdd(counter, 1u) == (uint32_t)gridDim.x - 1u);
    __syncthreads();
    if (!s_last) return;
    __threadfence();  // acquire side

    // Final reduce over slots[RGRID][32]; rows are 128 B -> each 32-lane
    // group reads one coalesced row per iteration. 256 loads/thread, fully
    // pipelined: ~2-3 us tail.
    int j   = threadIdx.x & 31;
    int grp = threadIdx.x >> 5;            // 8 row groups
    bool isMin = (j < NCOL);
    float acc = isMin ? INFINITY : -INFINITY;
    for (int r = grp; r < RGRID; r += 8) {
        float v = __hip_atomic_load(&slots[(size_t)r * 32 + j],
                                    __ATOMIC_RELAXED, __HIP_MEMORY_SCOPE_AGENT);
        acc = isMin ? fminf(acc, v) : fmaxf(acc, v);
    }
    __shared__ float red[8][32];
    red[grp][j] = acc;
    __syncthreads();
    if (threadIdx.x < NCOL) {
        int c = threadIdx.x;
        float mn = red[0][c], mx = red[0][NCOL + c];
        #pragma unroll
        for (int g2 = 1; g2 < 8; ++g2) {
            mn = fminf(mn, red[g2][c]);
            mx = fmaxf(mx, red[g2][NCOL + c]);
        }
        float r = mx - mn;
        if (r == 0.0f) r = 1.0f;
        finals[c]        = 2.0f / r;                 // scale
        finals[NCOL + c] = -2.0f * mn / r - 1.0f;    // offset
        // plain stores: kernel-boundary release makes these visible to pass 2
    }
}

// out = w0*xn + w1*xn^2 + w2*xn^3 + w3*exp(xn) + w4*log(|xn|+1) + w5*sqrt(|xn|)
//     + w6*tanh(xn) + w7*sin(xn) + w8*|xn| + bias      (xn in [-1,1] -> clips no-op)
__device__ __forceinline__ float eval_basis(float xn, const float* w, float b) {
    float ax = fabsf(xn);
    float x2 = xn * xn;
    float x3 = x2 * xn;
    float e  = __expf(xn);
    float e2 = e * e;                               // exp(2*xn)
    float t  = 1.0f - 2.0f * __frcp_rn(e2 + 1.0f);  // tanh
    float l  = __logf(ax + 1.0f);
    float sq = __fsqrt_rn(ax);
    float sn = __sinf(xn);
    float r = b;
    r = fmaf(w[0], xn, r);
    r = fmaf(w[1], x2, r);
    r = fmaf(w[2], x3, r);
    r = fmaf(w[3], e,  r);
    r = fmaf(w[4], l,  r);
    r = fmaf(w[5], sq, r);
    r = fmaf(w[6], t,  r);
    r = fmaf(w[7], sn, r);
    r = fmaf(w[8], ax, r);
    return r;
}

__global__ void __launch_bounds__(256) feature_kernel(const v4f* __restrict__ x,
                                                      v4f* __restrict__ out,
                                                      const float* __restrict__ finals,
                                                      const float* __restrict__ wts,
                                                      const float* __restrict__ bias,
                                                      int n4) {
    __shared__ float s_scale[NCOL], s_off[NCOL], s_w[9];
    if (threadIdx.x < NCOL) {
        s_scale[threadIdx.x] = finals[threadIdx.x];
        s_off[threadIdx.x]   = finals[NCOL + threadIdx.x];
    }
    if (threadIdx.x < 9) s_w[threadIdx.x] = wts[threadIdx.x];
    __syncthreads();

    int tid = blockIdx.x * blockDim.x + threadIdx.x;
    int stride = gridDim.x * blockDim.x;   // multiple of 4 -> column group fixed
    int g = (tid & 3) * 4;                 // this thread's 4 columns
    float sc0 = s_scale[g + 0], of0 = s_off[g + 0];
    float sc1 = s_scale[g + 1], of1 = s_off[g + 1];
    float sc2 = s_scale[g + 2], of2 = s_off[g + 2];
    float sc3 = s_scale[g + 3], of3 = s_off[g + 3];
    float w[9];
    #pragma unroll
    for (int k = 0; k < 9; ++k) w[k] = s_w[k];
    float b = bias[0];

    for (int i = tid; i < n4; i += stride) {
        v4f v = x[i];
        v4f o;
        o.x = eval_basis(fmaf(v.x, sc0, of0), w, b);
        o.y = eval_basis(fmaf(v.y, sc1, of1), w, b);
        o.z = eval_basis(fmaf(v.z, sc2, of2), w, b);
        o.w = eval_basis(fmaf(v.w, sc3, of3), w, b);
        // nontemporal: out is never re-read; don't evict x from L2/L3
        __builtin_nontemporal_store(o, &out[i]);
    }
}

extern "C" void kernel_launch(void* const* d_in, const int* in_sizes, int n_in,
                              void* d_out, int out_size, void* d_ws, size_t ws_size,
                              hipStream_t stream) {
    const float* x    = (const float*)d_in[0];
    const float* wts  = (const float*)d_in[1];
    const float* bias = (const float*)d_in[2];
    float* out = (float*)d_out;

    float*    finals  = (float*)d_ws;            // [32]
    uint32_t* counter = (uint32_t*)d_ws + 32;    // [1]
    float*    slots   = (float*)d_ws + 64;       // [RGRID][32], 256-B aligned

    int n  = in_sizes[0];       // N * 16 elements
    int n4 = n / 4;             // exact: 16e6 / 4

    // only the arrival counter needs init (slots are written before read)
    hipMemsetAsync(counter, 0, sizeof(uint32_t), stream);

    colreduce<<<RGRID, 256, 0, stream>>>((const v4f*)x, finals, slots, counter, n4);
    feature_kernel<<<4096, 256, 0, stream>>>((const v4f*)x, (v4f*)out, finals,
                                             wts, bias, n4);
}

// Round 2
// 130.390 us; speedup vs baseline: 2.4450x; 2.4450x over previous
//
#include <hip/hip_runtime.h>
#include <stdint.h>

#define NCOL 16
#define NGRP 64   // atomic slot groups: contention per address = 2048/NGRP = 32
typedef float v4f __attribute__((ext_vector_type(4)));

// ---- ordered-uint mapping for float atomic min/max ----
// fkey is monotonic: a<b <=> fkey(a)<fkey(b).
// Min slot:  atomicMin(fkey(f)),  identity 0xFFFFFFFF.
// Max slot:  atomicMin(fkey(-f)), identity 0xFFFFFFFF  (order-reversed map),
//            decode as -fkey_dec(k).
// -> ALL slots share identity 0xFFFFFFFF: a single hipMemsetAsync.
__device__ __forceinline__ uint32_t fkey(float f) {
    uint32_t u = __float_as_uint(f);
    return (u & 0x80000000u) ? ~u : (u | 0x80000000u);
}
__device__ __forceinline__ float fkey_dec(uint32_t k) {
    uint32_t u = (k & 0x80000000u) ? (k ^ 0x80000000u) : ~k;
    return __uint_as_float(u);
}

// Column-wise min/max over x[N,16] row-major, read as float4.
// mm layout: [NGRP][32] u32 -- per-group {minkey[16], maxkey[16]}.
// Each block atomically folds its 32 partials into group (blockIdx.x & 63):
// 32 same-address RMWs per slot instead of round-0's 2048 (64x less
// serialization at the coherence point).
__global__ void __launch_bounds__(256) colreduce(const v4f* __restrict__ x,
                                                 uint32_t* __restrict__ mm, int n4) {
    int tid = blockIdx.x * blockDim.x + threadIdx.x;
    int stride = gridDim.x * blockDim.x;   // 256-thread blocks -> multiple of 4
    float mn0 = INFINITY, mn1 = INFINITY, mn2 = INFINITY, mn3 = INFINITY;
    float mx0 = -INFINITY, mx1 = -INFINITY, mx2 = -INFINITY, mx3 = -INFINITY;
    for (int i = tid; i < n4; i += stride) {
        v4f v = x[i];   // regular load: populates L2/L3 so pass 2 hits L3
        mn0 = fminf(mn0, v.x); mx0 = fmaxf(mx0, v.x);
        mn1 = fminf(mn1, v.y); mx1 = fmaxf(mx1, v.y);
        mn2 = fminf(mn2, v.z); mx2 = fmaxf(mx2, v.z);
        mn3 = fminf(mn3, v.w); mx3 = fmaxf(mx3, v.w);
    }
    // Butterfly across the 16 lanes sharing the same (lane&3) column group.
    #pragma unroll
    for (int off = 4; off < 64; off <<= 1) {
        mn0 = fminf(mn0, __shfl_xor(mn0, off)); mx0 = fmaxf(mx0, __shfl_xor(mx0, off));
        mn1 = fminf(mn1, __shfl_xor(mn1, off)); mx1 = fmaxf(mx1, __shfl_xor(mx1, off));
        mn2 = fminf(mn2, __shfl_xor(mn2, off)); mx2 = fmaxf(mx2, __shfl_xor(mx2, off));
        mn3 = fminf(mn3, __shfl_xor(mn3, off)); mx3 = fmaxf(mx3, __shfl_xor(mx3, off));
    }
    __shared__ float smn[4][NCOL], smx[4][NCOL];
    int wave = threadIdx.x >> 6;
    int lane = threadIdx.x & 63;
    if (lane < 4) {           // lane l holds the full wave reduction for group l
        int g = lane * 4;
        smn[wave][g + 0] = mn0; smx[wave][g + 0] = mx0;
        smn[wave][g + 1] = mn1; smx[wave][g + 1] = mx1;
        smn[wave][g + 2] = mn2; smx[wave][g + 2] = mx2;
        smn[wave][g + 3] = mn3; smx[wave][g + 3] = mx3;
    }
    __syncthreads();
    if (threadIdx.x < NCOL) {
        int c = threadIdx.x;
        float m = fminf(fminf(smn[0][c], smn[1][c]), fminf(smn[2][c], smn[3][c]));
        float M = fmaxf(fmaxf(smx[0][c], smx[1][c]), fmaxf(smx[2][c], smx[3][c]));
        uint32_t* grp = mm + (size_t)(blockIdx.x & (NGRP - 1)) * 32;
        atomicMin(&grp[c], fkey(m));
        atomicMin(&grp[NCOL + c], fkey(-M));   // reversed map: max via atomicMin
    }
}

// out = w0*xn + w1*xn^2 + w2*xn^3 + w3*exp(xn) + w4*log(|xn|+1) + w5*sqrt(|xn|)
//     + w6*tanh(xn) + w7*sin(xn) + w8*|xn| + bias      (xn in [-1,1] -> clips no-op)
__device__ __forceinline__ float eval_basis(float xn, const float* w, float b) {
    float ax = fabsf(xn);
    float x2 = xn * xn;
    float x3 = x2 * xn;
    float e  = __expf(xn);
    float e2 = e * e;                               // exp(2*xn)
    float t  = 1.0f - 2.0f * __frcp_rn(e2 + 1.0f);  // tanh
    float l  = __logf(ax + 1.0f);
    float sq = __fsqrt_rn(ax);
    float sn = __sinf(xn);
    float r = b;
    r = fmaf(w[0], xn, r);
    r = fmaf(w[1], x2, r);
    r = fmaf(w[2], x3, r);
    r = fmaf(w[3], e,  r);
    r = fmaf(w[4], l,  r);
    r = fmaf(w[5], sq, r);
    r = fmaf(w[6], t,  r);
    r = fmaf(w[7], sn, r);
    r = fmaf(w[8], ax, r);
    return r;
}

__global__ void __launch_bounds__(256) feature_kernel(const v4f* __restrict__ x,
                                                      v4f* __restrict__ out,
                                                      const uint32_t* __restrict__ mm,
                                                      const float* __restrict__ wts,
                                                      const float* __restrict__ bias,
                                                      int n4) {
    // Combine the NGRP partial-key groups in parallel: thread t reduces
    // column j = t&31 over 8 rows (coalesced 128-B row reads, L2-hot).
    __shared__ uint32_t s_part[8][32];
    __shared__ float s_scale[NCOL], s_off[NCOL], s_w[9];
    {
        int j = threadIdx.x & 31;
        int r0 = threadIdx.x >> 5;            // 8 row groups
        uint32_t k = 0xFFFFFFFFu;
        #pragma unroll
        for (int r = 0; r < NGRP / 8; ++r)
            k = min(k, mm[(size_t)(r * 8 + r0) * 32 + j]);
        s_part[r0][j] = k;
    }
    if (threadIdx.x < 9) s_w[threadIdx.x] = wts[threadIdx.x];
    __syncthreads();
    if (threadIdx.x < NCOL) {
        int c = threadIdx.x;
        uint32_t kmn = s_part[0][c], kmx = s_part[0][NCOL + c];
        #pragma unroll
        for (int g2 = 1; g2 < 8; ++g2) {
            kmn = min(kmn, s_part[g2][c]);
            kmx = min(kmx, s_part[g2][NCOL + c]);
        }
        float mn = fkey_dec(kmn);
        float mx = -fkey_dec(kmx);              // reversed-map decode
        float r = mx - mn;
        if (r == 0.0f) r = 1.0f;
        s_scale[c] = 2.0f / r;
        s_off[c]   = -2.0f * mn / r - 1.0f;
    }
    __syncthreads();

    int tid = blockIdx.x * blockDim.x + threadIdx.x;
    int stride = gridDim.x * blockDim.x;   // multiple of 4 -> column group fixed
    int g = (tid & 3) * 4;                 // this thread's 4 columns
    float sc0 = s_scale[g + 0], of0 = s_off[g + 0];
    float sc1 = s_scale[g + 1], of1 = s_off[g + 1];
    float sc2 = s_scale[g + 2], of2 = s_off[g + 2];
    float sc3 = s_scale[g + 3], of3 = s_off[g + 3];
    float w[9];
    #pragma unroll
    for (int k = 0; k < 9; ++k) w[k] = s_w[k];
    float b = bias[0];

    for (int i = tid; i < n4; i += stride) {
        v4f v = x[i];
        v4f o;
        o.x = eval_basis(fmaf(v.x, sc0, of0), w, b);
        o.y = eval_basis(fmaf(v.y, sc1, of1), w, b);
        o.z = eval_basis(fmaf(v.z, sc2, of2), w, b);
        o.w = eval_basis(fmaf(v.w, sc3, of3), w, b);
        // nontemporal: out is never re-read; don't evict x from L2/L3
        __builtin_nontemporal_store(o, &out[i]);
    }
}

extern "C" void kernel_launch(void* const* d_in, const int* in_sizes, int n_in,
                              void* d_out, int out_size, void* d_ws, size_t ws_size,
                              hipStream_t stream) {
    const float* x    = (const float*)d_in[0];
    const float* wts  = (const float*)d_in[1];
    const float* bias = (const float*)d_in[2];
    float* out = (float*)d_out;
    uint32_t* mm = (uint32_t*)d_ws;     // [NGRP][32] keys

    int n  = in_sizes[0];       // N * 16 elements
    int n4 = n / 4;             // exact: 16e6 / 4

    // single init: every slot's identity is 0xFFFFFFFF (see fkey comment)
    hipMemsetAsync(mm, 0xFF, (size_t)NGRP * 32 * sizeof(uint32_t), stream);

    colreduce<<<2048, 256, 0, stream>>>((const v4f*)x, mm, n4);
    feature_kernel<<<4096, 256, 0, stream>>>((const v4f*)x, (v4f*)out, mm,
                                             wts, bias, n4);
}